// Round 13
// baseline (257.080 us; speedup 1.0000x reference)
//
#include <hip/hip_runtime.h>
#include <hip/hip_fp16.h>

#define XDIM 256
#define YDIM 256
#define ZDIM 32
#define NT 384
#define NA 180
#define AG 2                      // angles per block
#define SW 263                    // 8B cells per staged row
#define SR 38                     // 3 pad + 32 data + 3 pad (strip axis)
#define NST 8                     // strips per block
#define SMEM_BYTES 79952          // 38*263*8 -> TWO blocks/CU (<=80KB)

// Block = one z-QUAD x 2 angles, looping over 8 strips of 32 rows along the
// fast-crossing axis. Same measured structure as the 238us round-12 kernel
// (z-quad uint2 cells: 1 geometry + 4 ds_read_b64 feed 4 z-outputs) but the
// strip is halved so LDS = 79,952B < 80KB -> 2 blocks/CU = 32 waves/CU.
// Round-12 counters showed per-SIMD VALU issue ~25-30% and LDS ~47%:
// latency-bound with an exposed staging-barrier drain. Two co-resident
// blocks interleave barrier phases with compute. Unlike rounds 3/5 this
// keeps VGPR=64 naturally (no forced bounds; identical code shape) and
// blocks still own whole rays (no atomics, no cross-block idleness; axis
// choice keeps |row slope|>=0.695 so every ray crosses all 8 strips).
// Per-strip partition cost cut by hoisting the global t-interval and the
// boundary reciprocal per angle: ta = fmaf(st, 32/cr, b0); identical fp
// expressions for adjacent strip bounds -> exact partition. Pad 3 +
// ceil'd starts keep every executed tap staged (verified scheme).
__global__ __launch_bounds__(1024) void proj_kernel(
    const float* __restrict__ vol, const float* __restrict__ phis,
    float* __restrict__ out) {
  extern __shared__ char smem[];
  uint2* sl = reinterpret_cast<uint2*>(smem);
  float4* ps = reinterpret_cast<float4*>(smem);  // aliases slice when dead

  const int tid = threadIdx.x;
  const int zq = blockIdx.x;  // 0..7 z-quad
  const int ag = blockIdx.y;  // 0..89 angle group
  const int col = tid & 255;
  const int q = tid >> 8;     // t-quarter (it % 4 == q)
  const float u = (float)col - 127.5f;

  // block-uniform axis from the group's first angle:
  // ax=1 -> strip axis y (row=y,col=x); ax=0 -> strip axis x (row=x,col=y)
  const float phi0 = phis[ag * AG] * 0.017453292519943295f;
  const int ax = (fabsf(sinf(phi0)) >= fabsf(cosf(phi0))) ? 1 : 0;

  // per-angle hoisted state: c,s + strip-boundary lerp (b0,stp) + interval
  float c_[AG], s_[AG], b0_[AG], stp_[AG];
  int glo_[AG], ghi_[AG];
#pragma unroll
  for (int j = 0; j < AG; ++j) {
    const float phi = phis[ag * AG + j] * 0.017453292519943295f;
    const float c = cosf(phi), s = sinf(phi);
    c_[j] = c; s_[j] = s;
    const float bx = fmaf(u, -s, 127.5f);
    const float by = fmaf(u, c, 127.5f);
    const float cr = ax ? s : c, br = ax ? by : bx;  // |cr| >= 0.695
    const float cc = ax ? c : s, bc = ax ? bx : by;
    // global t-interval (widen +-2; ceil start keeps taps in the 3-pad)
    float t1 = (-1.f - br) / cr + 191.5f;
    float t2 = (256.f - br) / cr + 191.5f;
    float flo = fmaxf(0.f, fminf(t1, t2) - 2.f);
    float fhi = fminf((float)NT, fmaxf(t1, t2) + 2.f);
    if (fabsf(cc) < 1e-6f) {
      if (bc <= -1.f || bc >= 256.f) { flo = 1.f; fhi = 0.f; }
    } else {
      float t3 = (-1.f - bc) / cc + 191.5f;
      float t4 = (256.f - bc) / cc + 191.5f;
      flo = fmaxf(flo, fminf(t3, t4) - 2.f);
      fhi = fminf(fhi, fmaxf(t3, t4) + 2.f);
    }
    glo_[j] = (int)ceilf(flo);
    ghi_[j] = (int)fhi;
    // strip boundary t(row=32*st) = fmaf(st, stp, b0)
    const float rcr = 1.f / cr;
    b0_[j] = fmaf(-br, rcr, 191.5f);
    stp_[j] = 32.f * rcr;
  }

  float4 acc[AG];
#pragma unroll
  for (int j = 0; j < AG; ++j) acc[j] = make_float4(0.f, 0.f, 0.f, 0.f);

  const float* vb = vol + (zq * 4) * (YDIM * XDIM);  // 4 slices, stride 64K

  for (int st = 0; st < NST; ++st) {
    const int gr0 = st * 32 - 3;  // global strip-axis index of local row 0
    __syncthreads();              // prior strip reads / psum done

    // col pads: lw in {0,1,2} u {259..262}, all 38 rows (266 threads)
    if (tid < SR * 7) {
      int r = tid / 7;
      int c7 = tid - r * 7;
      int lw = c7 < 3 ? c7 : c7 + 256;
      sl[r * SW + lw] = make_uint2(0u, 0u);
    }
    if (ax) {
      // cell(r,w)=vol[z][gr0+r][w]; 38*256=9728 cells, coalesced along x
      for (int i = 0; i < 10; ++i) {
        int k = tid + (i << 10);
        if (k < SR * 256) {
          int r = k >> 8, x = k & 255, gr = gr0 + r;
          uint2 v = make_uint2(0u, 0u);
          if ((unsigned)gr < 256u) {
            int gi = gr * XDIM + x;
            __half2 p = __floats2half2_rn(vb[gi], vb[gi + 65536]);
            __half2 qq = __floats2half2_rn(vb[gi + 131072], vb[gi + 196608]);
            v.x = *reinterpret_cast<unsigned*>(&p);
            v.y = *reinterpret_cast<unsigned*>(&qq);
          }
          sl[r * SW + x + 3] = v;
        }
      }
    } else {
      // cell(r,w)=vol[z][y=w][x=gr0+r]; coalesced global reads along x,
      // transpose happens at the LDS write (stride-SW, bank-spread, cheap)
      // pass A: r=0..31 -> half-wave reads 32 consecutive floats
      for (int i = 0; i < 8; ++i) {
        int k = tid + (i << 10);
        int r = k & 31, y = k >> 5, gx = gr0 + r;
        uint2 v = make_uint2(0u, 0u);
        if ((unsigned)gx < 256u) {
          int gi = y * XDIM + gx;
          __half2 p = __floats2half2_rn(vb[gi], vb[gi + 65536]);
          __half2 qq = __floats2half2_rn(vb[gi + 131072], vb[gi + 196608]);
          v.x = *reinterpret_cast<unsigned*>(&p);
          v.y = *reinterpret_cast<unsigned*>(&qq);
        }
        sl[r * SW + y + 3] = v;
      }
      // pass B: r=32..37 (6 rows x 256 y), width-8 tiles, 2/8 lanes masked
      for (int i = 0; i < 2; ++i) {
        int k = tid + (i << 10);
        int rb = k & 7, y = k >> 3;
        if (rb < 6) {
          int r = 32 + rb, gx = gr0 + r;
          uint2 v = make_uint2(0u, 0u);
          if ((unsigned)gx < 256u) {
            int gi = y * XDIM + gx;
            __half2 p = __floats2half2_rn(vb[gi], vb[gi + 65536]);
            __half2 qq = __floats2half2_rn(vb[gi + 131072], vb[gi + 196608]);
            v.x = *reinterpret_cast<unsigned*>(&p);
            v.y = *reinterpret_cast<unsigned*>(&qq);
          }
          sl[r * SW + y + 3] = v;
        }
      }
    }
    __syncthreads();

    const int KOFF = (3 - 32 * st) * SW + 3;  // ai = r0*SW + w0 + KOFF
#pragma unroll
    for (int j = 0; j < AG; ++j) {
      const float c = c_[j], s = s_[j];
      const float bx = fmaf(u, -s, 127.5f);
      const float by = fmaf(u, c, 127.5f);
      const float cr = ax ? s : c, br = ax ? by : bx;
      const float cc = ax ? c : s, bc = ax ? bx : by;
      const int glo = glo_[j], ghi = ghi_[j];
      // strip bounds: identical fp expressions for adjacent strips
      const float ta = fmaf((float)st, stp_[j], b0_[j]);
      const float tb = fmaf((float)(st + 1), stp_[j], b0_[j]);
      const int ia = (int)ceilf(ta);
      const int ib = (int)ceilf(tb);
      int lo, hi;
      if (cr > 0.f) {
        lo = (st == 0) ? glo : max(glo, ia);
        hi = (st == NST - 1) ? ghi : min(ghi, ib);
      } else {
        lo = (st == NST - 1) ? glo : max(glo, ib);
        hi = (st == 0) ? ghi : min(ghi, ia);
      }
      const int start = lo + ((q - lo) & 3);
      const int d = hi - start;
      const int n = d > 0 ? (d + 3) >> 2 : 0;
      float t = (float)start - 191.5f;  // half-integers: t += 4 exact in fp32
      float a0 = acc[j].x, a1 = acc[j].y, a2 = acc[j].z, a3 = acc[j].w;
#pragma unroll 2
      for (int k = 0; k < n; ++k, t += 4.f) {
        float rr = fmaf(t, cr, br);
        float ww = fmaf(t, cc, bc);
        float r0f = floorf(rr), w0f = floorf(ww);
        float fr = rr - r0f, fw = ww - w0f;
        int ai = (int)fmaf(r0f, (float)SW, w0f) + KOFF;  // exact: |.| < 2^24
        uint2 D00 = sl[ai], D01 = sl[ai + 1];
        uint2 D10 = sl[ai + SW], D11 = sl[ai + SW + 1];
        __half2 fw2 = __float2half2_rn(fw);
        __half2 e00 = *reinterpret_cast<__half2*>(&D00.x);
        __half2 o00 = *reinterpret_cast<__half2*>(&D00.y);
        __half2 e01 = *reinterpret_cast<__half2*>(&D01.x);
        __half2 o01 = *reinterpret_cast<__half2*>(&D01.y);
        __half2 e10 = *reinterpret_cast<__half2*>(&D10.x);
        __half2 o10 = *reinterpret_cast<__half2*>(&D10.y);
        __half2 e11 = *reinterpret_cast<__half2*>(&D11.x);
        __half2 o11 = *reinterpret_cast<__half2*>(&D11.y);
        // col-lerp in packed fp16: z01 and z23 simultaneously, both rows
        __half2 hxa = __hfma2(__hsub2(e01, e00), fw2, e00);  // top, z0z1
        __half2 hxb = __hfma2(__hsub2(o01, o00), fw2, o00);  // top, z2z3
        __half2 hya = __hfma2(__hsub2(e11, e10), fw2, e10);  // bot, z0z1
        __half2 hyb = __hfma2(__hsub2(o11, o10), fw2, o10);  // bot, z2z3
        float omfr = 1.f - fr;
        a0 = fmaf(__low2float(hxa), omfr, a0);
        a0 = fmaf(__low2float(hya), fr, a0);
        a1 = fmaf(__high2float(hxa), omfr, a1);
        a1 = fmaf(__high2float(hya), fr, a1);
        a2 = fmaf(__low2float(hxb), omfr, a2);
        a2 = fmaf(__low2float(hyb), fr, a2);
        a3 = fmaf(__high2float(hxb), omfr, a3);
        a3 = fmaf(__high2float(hyb), fr, a3);
      }
      acc[j] = make_float4(a0, a1, a2, a3);
    }
  }

  // reduce 4 t-quarters (ps aliases dead slice) and write 4 z per angle
#pragma unroll
  for (int j = 0; j < AG; ++j) {
    __syncthreads();
    ps[tid] = acc[j];
    __syncthreads();
    if (tid < 256) {
      float4 A = ps[col], B = ps[256 + col], C = ps[512 + col],
             D = ps[768 + col];
      const int a = ag * AG + j;
      const int zb = zq * 4;
      out[(a * ZDIM + zb + 0) * XDIM + col] = A.x + B.x + C.x + D.x;
      out[(a * ZDIM + zb + 1) * XDIM + col] = A.y + B.y + C.y + D.y;
      out[(a * ZDIM + zb + 2) * XDIM + col] = A.z + B.z + C.z + D.z;
      out[(a * ZDIM + zb + 3) * XDIM + col] = A.w + B.w + C.w + D.w;
    }
  }
}

extern "C" void kernel_launch(void* const* d_in, const int* in_sizes, int n_in,
                              void* d_out, int out_size, void* d_ws, size_t ws_size,
                              hipStream_t stream) {
  const float* vol = (const float*)d_in[0];
  const float* phis = (const float*)d_in[1];
  float* out = (float*)d_out;
  (void)hipFuncSetAttribute((const void*)proj_kernel,
                            hipFuncAttributeMaxDynamicSharedMemorySize,
                            SMEM_BYTES);
  dim3 grid(ZDIM / 4, NA / AG);
  proj_kernel<<<grid, 1024, SMEM_BYTES, stream>>>(vol, phis, out);
}

// Round 23
// 244.554 us; speedup vs baseline: 1.0512x; 1.0512x over previous
//
#include <hip/hip_runtime.h>
#include <hip/hip_fp16.h>

#define XDIM 256
#define YDIM 256
#define ZDIM 32
#define NT 384
#define NA 180
#define AG 2                      // angles per block
#define SW 263                    // 8B cells per staged row
#define SR 38                     // 3 pad + 32 data + 3 pad (strip axis)
#define NST 8                     // strips of 32 data rows
#define SLICE (SR * SW)           // 9994 cells = 79952 B per buffer
#define SMEM_BYTES (2 * SLICE * 8)  // 159904 <= 163840 (fits! r20 bug: 64-row
                                    // strips gave 294560 > LDS -> launch fail)

// Round-12 winner's compute (z-quad uint2 cells) + T14 double-buffered
// async staging, now with 32-row strips so TWO buffers fit in LDS.
// Round-20 failure diagnosis: absmax 67.5 == max|ref| -> output all zeros
// -> launch failed (SMEM 294560 B > 160KB capacity, errors silently
// swallowed). Fix: SR=38/NST=8 (geometry verified correct in round 13,
// absmax 0.25) x two 79952B buffers = 159904 B. Schedule per strip:
// issue next strip's global loads BEFORE compute (burst A before angle 0,
// burst B before angle 1; 5xfloat4/burst -> 20 staging VGPRs), ds_write
// to the OTHER buffer after compute covers the HBM latency, ONE barrier
// per strip. Barrier count == round-12 (8), so the ~60-80us of exposed
// serial staging in round-12's 201us is the net target. Writes of OOB
// rows store zeros (row pads); col pads zeroed once for both buffers.
// Strip bounds use identical fp expressions in adjacent strips -> exact
// partition. launch_bounds(1024,4): allocator gets 128 regs (1 block of
// 16 waves needs exactly 4 waves/EU), avoiding round-3's forced spill.
__global__ __launch_bounds__(1024, 4) void proj_kernel(
    const float* __restrict__ vol, const float* __restrict__ phis,
    float* __restrict__ out) {
  extern __shared__ char smem[];
  uint2* sl = reinterpret_cast<uint2*>(smem);    // buf b at sl + b*SLICE
  float4* ps = reinterpret_cast<float4*>(smem);  // aliases after compute

  const int tid = threadIdx.x;
  const int zq = blockIdx.x;  // 0..7 z-quad
  const int ag = blockIdx.y;  // 0..89 angle group
  const int col = tid & 255;
  const int q = tid >> 8;     // t-quarter (it % 4 == q)
  const float u = (float)col - 127.5f;

  const float phi0 = phis[ag * AG] * 0.017453292519943295f;
  const int ax = (fabsf(sinf(phi0)) >= fabsf(cosf(phi0))) ? 1 : 0;

  const float phiB = phis[ag * AG + 1] * 0.017453292519943295f;
  const float c0 = cosf(phi0), s0 = sinf(phi0);
  const float c1 = cosf(phiB), s1 = sinf(phiB);

  float4 acc0 = make_float4(0.f, 0.f, 0.f, 0.f);
  float4 acc1 = make_float4(0.f, 0.f, 0.f, 0.f);

  const float* vb = vol + (zq * 4) * (YDIM * XDIM);  // 4 slices, 64K stride

  // ---- staging: 10 slots of 1024 cells; burst b covers ii = b*5..b*5+4 ----
  float4 fS[5];  // one burst of raw floats (20 VGPRs, reused A/B)

  auto LOAD = [&](int st1, int b) {
    const int gr0 = st1 * 32 - 3;
#pragma unroll
    for (int i = 0; i < 5; ++i) {
      const int ii = b * 5 + i;
      const int k = tid + (ii << 10);
      float4 val = make_float4(0.f, 0.f, 0.f, 0.f);
      if (ax) {
        if (k < SR * 256) {  // slot 9 half-masked (9728 cells)
          int r = k >> 8, x = k & 255, gr = gr0 + r;
          if ((unsigned)gr < 256u) {
            int gi = gr * XDIM + x;
            val.x = vb[gi];          val.y = vb[gi + 65536];
            val.z = vb[gi + 131072]; val.w = vb[gi + 196608];
          }
        }
      } else {
        if (ii < 8) {  // pass A: rows 0..31, coalesced along x
          int r = k & 31, y = k >> 5, gx = gr0 + r;
          if ((unsigned)gx < 256u) {
            int gi = y * XDIM + gx;
            val.x = vb[gi];          val.y = vb[gi + 65536];
            val.z = vb[gi + 131072]; val.w = vb[gi + 196608];
          }
        } else {       // pass B: rows 32..37 (6x256 via 2048 lanes)
          int kb = tid + ((ii - 8) << 10);
          int rb = kb & 7, y = kb >> 3;
          if (rb < 6) {
            int gx = gr0 + 32 + rb;
            if ((unsigned)gx < 256u) {
              int gi = y * XDIM + gx;
              val.x = vb[gi];          val.y = vb[gi + 65536];
              val.z = vb[gi + 131072]; val.w = vb[gi + 196608];
            }
          }
        }
      }
      fS[i] = val;
    }
  };

  auto WRITE = [&](int st1, int b) {
    uint2* buf = sl + (st1 & 1) * SLICE;
#pragma unroll
    for (int i = 0; i < 5; ++i) {
      const int ii = b * 5 + i;
      const int k = tid + (ii << 10);
      __half2 p = __floats2half2_rn(fS[i].x, fS[i].y);
      __half2 qq = __floats2half2_rn(fS[i].z, fS[i].w);
      uint2 val;
      val.x = *reinterpret_cast<unsigned*>(&p);
      val.y = *reinterpret_cast<unsigned*>(&qq);
      if (ax) {
        if (k < SR * 256) {
          int r = k >> 8, x = k & 255;
          buf[r * SW + x + 3] = val;
        }
      } else {
        if (ii < 8) {
          int r = k & 31, y = k >> 5;
          buf[r * SW + y + 3] = val;
        } else {
          int kb = tid + ((ii - 8) << 10);
          int rb = kb & 7, y = kb >> 3;
          if (rb < 6) buf[(32 + rb) * SW + y + 3] = val;
        }
      }
    }
  };

  // compute one (strip, angle): identical math to verified rounds 12/13
  auto COMPUTE = [&](int st, float c, float s, float4& A) {
    const int KOFF = (3 - 32 * st) * SW + 3 + (st & 1) * SLICE;
    const float bx = fmaf(u, -s, 127.5f);
    const float by = fmaf(u, c, 127.5f);
    const float cr = ax ? s : c, br = ax ? by : bx;  // |cr| >= 0.695
    const float cc = ax ? c : s, bc = ax ? bx : by;
    float t1 = (-1.f - br) / cr + 191.5f;
    float t2 = (256.f - br) / cr + 191.5f;
    float flo = fmaxf(0.f, fminf(t1, t2) - 2.f);
    float fhi = fminf((float)NT, fmaxf(t1, t2) + 2.f);
    if (fabsf(cc) < 1e-6f) {
      if (bc <= -1.f || bc >= 256.f) { flo = 1.f; fhi = 0.f; }
    } else {
      float t3 = (-1.f - bc) / cc + 191.5f;
      float t4 = (256.f - bc) / cc + 191.5f;
      flo = fmaxf(flo, fminf(t3, t4) - 2.f);
      fhi = fminf(fhi, fmaxf(t3, t4) + 2.f);
    }
    const int glo = (int)ceilf(flo);
    const int ghi = (int)fhi;
    // identical fp expressions in adjacent strips -> exact partition
    float ta = ((float)(32 * st) - br) / cr + 191.5f;
    float tb = ((float)(32 * st + 32) - br) / cr + 191.5f;
    int ia = (int)ceilf(ta);
    int ib = (int)ceilf(tb);
    int lo, hi;
    if (cr > 0.f) {
      lo = (st == 0) ? glo : max(glo, ia);
      hi = (st == NST - 1) ? ghi : min(ghi, ib);
    } else {
      lo = (st == NST - 1) ? glo : max(glo, ib);
      hi = (st == 0) ? ghi : min(ghi, ia);
    }
    const int start = lo + ((q - lo) & 3);
    const int d = hi - start;
    const int n = d > 0 ? (d + 3) >> 2 : 0;
    float t = (float)start - 191.5f;  // half-integers: t += 4 exact in fp32
    float a0 = A.x, a1 = A.y, a2 = A.z, a3 = A.w;
#pragma unroll 2
    for (int k2 = 0; k2 < n; ++k2, t += 4.f) {
      float rr = fmaf(t, cr, br);
      float ww = fmaf(t, cc, bc);
      float r0f = floorf(rr), w0f = floorf(ww);
      float fr = rr - r0f, fw = ww - w0f;
      int ai = (int)fmaf(r0f, (float)SW, w0f) + KOFF;  // exact: |.| < 2^24
      uint2 D00 = sl[ai], D01 = sl[ai + 1];
      uint2 D10 = sl[ai + SW], D11 = sl[ai + SW + 1];
      __half2 fw2 = __float2half2_rn(fw);
      __half2 e00 = *reinterpret_cast<__half2*>(&D00.x);
      __half2 o00 = *reinterpret_cast<__half2*>(&D00.y);
      __half2 e01 = *reinterpret_cast<__half2*>(&D01.x);
      __half2 o01 = *reinterpret_cast<__half2*>(&D01.y);
      __half2 e10 = *reinterpret_cast<__half2*>(&D10.x);
      __half2 o10 = *reinterpret_cast<__half2*>(&D10.y);
      __half2 e11 = *reinterpret_cast<__half2*>(&D11.x);
      __half2 o11 = *reinterpret_cast<__half2*>(&D11.y);
      __half2 hxa = __hfma2(__hsub2(e01, e00), fw2, e00);  // top, z0z1
      __half2 hxb = __hfma2(__hsub2(o01, o00), fw2, o00);  // top, z2z3
      __half2 hya = __hfma2(__hsub2(e11, e10), fw2, e10);  // bot, z0z1
      __half2 hyb = __hfma2(__hsub2(o11, o10), fw2, o10);  // bot, z2z3
      float omfr = 1.f - fr;
      a0 = fmaf(__low2float(hxa), omfr, a0);
      a0 = fmaf(__low2float(hya), fr, a0);
      a1 = fmaf(__high2float(hxa), omfr, a1);
      a1 = fmaf(__high2float(hya), fr, a1);
      a2 = fmaf(__low2float(hxb), omfr, a2);
      a2 = fmaf(__low2float(hyb), fr, a2);
      a3 = fmaf(__high2float(hxb), omfr, a3);
      a3 = fmaf(__high2float(hyb), fr, a3);
    }
    A = make_float4(a0, a1, a2, a3);
  };

  // ---- prologue: col pads (both buffers) + stage strip 0 serially ----
  if (tid < 2 * SR * 7) {
    int bi = tid / (SR * 7);
    int rr2 = tid - bi * (SR * 7);
    int r = rr2 / 7;
    int c7 = rr2 - r * 7;
    int lw = c7 < 3 ? c7 : c7 + 256;
    sl[bi * SLICE + r * SW + lw] = make_uint2(0u, 0u);
  }
  LOAD(0, 0); WRITE(0, 0);
  LOAD(0, 1); WRITE(0, 1);
  __syncthreads();

  // ---- main: prefetch strip st+1 around compute of strip st ----
#pragma unroll
  for (int st = 0; st < NST; ++st) {
    if (st < NST - 1) LOAD(st + 1, 0);   // issue burst A early
    COMPUTE(st, c0, s0, acc0);           // hides burst-A latency
    if (st < NST - 1) { WRITE(st + 1, 0); LOAD(st + 1, 1); }
    COMPUTE(st, c1, s1, acc1);           // hides burst-B latency
    if (st < NST - 1) WRITE(st + 1, 1);
    __syncthreads();                     // ONE barrier per strip
  }

  // ---- reduce 4 t-quarters (ps aliases dead buffers), write 4 z/angle ----
#pragma unroll
  for (int j = 0; j < AG; ++j) {
    __syncthreads();
    ps[tid] = j ? acc1 : acc0;
    __syncthreads();
    if (tid < 256) {
      float4 A = ps[col], B = ps[256 + col], C = ps[512 + col],
             D = ps[768 + col];
      const int a = ag * AG + j;
      const int zb = zq * 4;
      out[(a * ZDIM + zb + 0) * XDIM + col] = A.x + B.x + C.x + D.x;
      out[(a * ZDIM + zb + 1) * XDIM + col] = A.y + B.y + C.y + D.y;
      out[(a * ZDIM + zb + 2) * XDIM + col] = A.z + B.z + C.z + D.z;
      out[(a * ZDIM + zb + 3) * XDIM + col] = A.w + B.w + C.w + D.w;
    }
  }
}

extern "C" void kernel_launch(void* const* d_in, const int* in_sizes, int n_in,
                              void* d_out, int out_size, void* d_ws, size_t ws_size,
                              hipStream_t stream) {
  const float* vol = (const float*)d_in[0];
  const float* phis = (const float*)d_in[1];
  float* out = (float*)d_out;
  (void)hipFuncSetAttribute((const void*)proj_kernel,
                            hipFuncAttributeMaxDynamicSharedMemorySize,
                            SMEM_BYTES);
  dim3 grid(ZDIM / 4, NA / AG);
  proj_kernel<<<grid, 1024, SMEM_BYTES, stream>>>(vol, phis, out);
}